// Round 10
// baseline (934.854 us; speedup 1.0000x reference)
//
#include <hip/hip_runtime.h>
#include <hip/hip_bf16.h>
#include <hip/hip_cooperative_groups.h>

namespace cg = cooperative_groups;

#define DIN 128
#define DHID 128
#define DCLS 64
#define BN_EPS 1e-5f
#define GEN_EPS 1e-7f

typedef __attribute__((ext_vector_type(8))) short short8;
typedef __attribute__((ext_vector_type(4))) float f32x4;

static __device__ __forceinline__ float bf2f(unsigned short u) {
    union { float f; unsigned int i; } x; x.i = ((unsigned int)u) << 16; return x.f;
}
static __device__ __forceinline__ unsigned short f2bf(float f) {
    union { float f; unsigned int i; } x; x.f = f;
    unsigned int r = x.i + 0x7fffu + ((x.i >> 16) & 1u);
    return (unsigned short)(r >> 16);
}
static __device__ __forceinline__ float bflo(unsigned int u) {
    union { float f; unsigned int i; } x; x.i = u << 16; return x.f;
}
static __device__ __forceinline__ float bfhi(unsigned int u) {
    union { float f; unsigned int i; } x; x.i = u & 0xffff0000u; return x.f;
}
static __device__ __forceinline__ unsigned int packbf(float lo, float hi) {
    return ((unsigned int)f2bf(hi) << 16) | f2bf(lo);
}

// ---------------- CSR build: one cooperative kernel, 6 phases ----------------
// phase0: zero counts+stats | phase1: histogram | phase2: block-local scans |
// phase3: scan of block sums | phase4: apply base, cursor, dinv | phase5: fill
__global__ __launch_bounds__(256) void k_csr(const int* __restrict__ src,
        const int* __restrict__ dst, int* __restrict__ counts, int* __restrict__ cursor,
        int* __restrict__ roff, int* __restrict__ bsum, int* __restrict__ srcs,
        float* __restrict__ dinv, float* __restrict__ stats, int N, int E) {
    cg::grid_group grid = cg::this_grid();
    __shared__ int ls[256];
    const int gsz = gridDim.x * 256;
    const int gtid = blockIdx.x * 256 + threadIdx.x;
    // phase 0: zero
    for (int i = gtid; i < N; i += gsz) counts[i] = 0;
    if (gtid < 1024) stats[gtid] = 0.f;
    grid.sync();
    // phase 1: histogram of dst
    for (int e = gtid; e < E; e += gsz) atomicAdd(&counts[dst[e]], 1);
    grid.sync();
    // phase 2: block-local exclusive prefix over 1024-chunks
    int nblk = (N + 1023) >> 10;
    if ((int)blockIdx.x < nblk) {
        int t = threadIdx.x;
        int base = blockIdx.x * 1024 + t * 4;
        int c0 = 0, c1 = 0, c2 = 0, c3 = 0;
        if (base + 3 < N) {
            int4 v = *(const int4*)(counts + base);
            c0 = v.x; c1 = v.y; c2 = v.z; c3 = v.w;
        } else {
            if (base + 0 < N) c0 = counts[base + 0];
            if (base + 1 < N) c1 = counts[base + 1];
            if (base + 2 < N) c2 = counts[base + 2];
            if (base + 3 < N) c3 = counts[base + 3];
        }
        ls[t] = c0 + c1 + c2 + c3;
        __syncthreads();
        for (int off = 1; off < 256; off <<= 1) {
            int v = (t >= off) ? ls[t - off] : 0;
            __syncthreads();
            ls[t] += v;
            __syncthreads();
        }
        int r = (t == 0) ? 0 : ls[t - 1];
        if (base + 0 < N) { roff[base + 0] = r; r += c0; }
        if (base + 1 < N) { roff[base + 1] = r; r += c1; }
        if (base + 2 < N) { roff[base + 2] = r; r += c2; }
        if (base + 3 < N) { roff[base + 3] = r; }
        if (t == 255) bsum[blockIdx.x] = ls[255];
    }
    grid.sync();
    // phase 3: exclusive scan of block sums (serial, nblk ~ 49)
    if (gtid == 0) {
        int run = 0;
        for (int j = 0; j < nblk; j++) { int v = bsum[j]; bsum[j] = run; run += v; }
    }
    grid.sync();
    // phase 4: add block base; init cursor, dinv
    for (int i = gtid; i < N; i += gsz) {
        int r = roff[i] + bsum[i >> 10];
        roff[i] = r; cursor[i] = r;
        dinv[i] = rsqrtf((float)(counts[i] + 1));
    }
    if (gtid == 0) roff[N] = E;
    grid.sync();
    // phase 5: fill srcs
    for (int e = gtid; e < E; e += gsz) {
        int d = dst[e];
        int p = atomicAdd(&cursor[d], 1);
        srcs[p] = src[e];
    }
}

// ---------------- all four weight transposes in one launch ----------------
__global__ void k_wt_all(const float* __restrict__ W0, const float* __restrict__ W1,
        const float* __restrict__ Wg1, const float* __restrict__ Wg2,
        unsigned short* __restrict__ w0t, unsigned short* __restrict__ w1t,
        unsigned short* __restrict__ wg1t, unsigned short* __restrict__ wg2t) {
    int i = blockIdx.x * 256 + threadIdx.x;
    const float* W; unsigned short* Wt; int Kk, Dd, j;
    if (i < 16384)      { W = W0;  Wt = w0t;  Kk = 128; Dd = 128; j = i; }
    else if (i < 32768) { W = W1;  Wt = w1t;  Kk = 128; Dd = 128; j = i - 16384; }
    else if (i < 65536) { W = Wg1; Wt = wg1t; Kk = 128; Dd = 256; j = i - 32768; }
    else if (i < 81920) { W = Wg2; Wt = wg2t; Kk = 256; Dd = 64;  j = i - 65536; }
    else return;
    int n = j / Kk, k = j - n * Kk;
    Wt[j] = f2bf(W[(size_t)k * Dd + n]);
}

// ---------------- GEMM: C[nrows,Dout] = op(A)[nrows,K] @ W[K,Dout] (+bias, *rowscale) ----------------
// SFIN: BN finalize inlined (scale/shift from raw sums in LDS preamble, relu fused on A).
// STATS: fuse per-column sum/sumsq of outputs via LDS + global atomics.
// HEAD: fuse row log_softmax (requires CTILE == Dout == 64, f32 out).
template<int K, int CTILE, bool ABF16, bool OBF16, bool STATS, bool HEAD, bool SFIN>
__global__ __launch_bounds__(256) void k_gemm(const void* __restrict__ Av,
        const unsigned short* __restrict__ Wt, const float* __restrict__ bias,
        const float* __restrict__ bnsum, const float* __restrict__ bnsq,
        const float* __restrict__ bng, const float* __restrict__ bnbeta, float invN,
        const float* __restrict__ rowscale,
        void* __restrict__ Cv, float* __restrict__ gsum, float* __restrict__ gsq,
        int nrows, int Dout) {
    constexpr int KP = 136;
    constexpr int NF = CTILE / 32;
    constexpr int BNSZ = SFIN ? 2 * K : 2;
    __shared__ unsigned short smem[(64 + CTILE) * KP];
    __shared__ float sBN[BNSZ];
    unsigned short* sA = smem;
    unsigned short* sW = smem + 64 * KP;
    const int tid = threadIdx.x;
    const int row0 = blockIdx.x * 64, col0 = blockIdx.y * CTILE;

    if (SFIN) {
        for (int c = tid; c < K; c += 256) {
            float mu = bnsum[c] * invN;
            float var = bnsq[c] * invN - mu * mu;
            float s = bng[c] * rsqrtf(var + BN_EPS);
            sBN[c] = s; sBN[K + c] = bnbeta[c] - mu * s;
        }
        __syncthreads();
    }

    const int w = tid >> 6, lane = tid & 63;
    const int wr = (w >> 1) * 32, wc = (w & 1) * (CTILE / 2);
    const int lr = lane & 15, kg = (lane >> 4) * 8;
    f32x4 acc[2][NF] = {};

    for (int kh = 0; kh < K; kh += 128) {
#pragma unroll
        for (int it = 0; it < 8; ++it) {
            int idx = (it * 256 + tid) * 4;
            int r = idx >> 7, c = idx & 127;
            int gr = row0 + r;
            float v0 = 0.f, v1 = 0.f, v2 = 0.f, v3 = 0.f;
            if (gr < nrows) {
                if (ABF16) {
                    ushort4 u = *(const ushort4*)((const unsigned short*)Av + (size_t)gr * K + kh + c);
                    v0 = bf2f(u.x); v1 = bf2f(u.y); v2 = bf2f(u.z); v3 = bf2f(u.w);
                } else {
                    float4 f = *(const float4*)((const float*)Av + (size_t)gr * K + kh + c);
                    v0 = f.x; v1 = f.y; v2 = f.z; v3 = f.w;
                }
                if (SFIN) {
                    int cc = kh + c;
                    v0 = fmaxf(v0 * sBN[cc + 0] + sBN[K + cc + 0], 0.f);
                    v1 = fmaxf(v1 * sBN[cc + 1] + sBN[K + cc + 1], 0.f);
                    v2 = fmaxf(v2 * sBN[cc + 2] + sBN[K + cc + 2], 0.f);
                    v3 = fmaxf(v3 * sBN[cc + 3] + sBN[K + cc + 3], 0.f);
                }
            }
            ushort4 o; o.x = f2bf(v0); o.y = f2bf(v1); o.z = f2bf(v2); o.w = f2bf(v3);
            *(ushort4*)(&sA[r * KP + c]) = o;
        }
#pragma unroll
        for (int it = 0; it < (CTILE * 128) / (256 * 8); ++it) {
            int idx = (it * 256 + tid) * 8;
            int r = idx >> 7, c = idx & 127;
            uint4 u = *(const uint4*)(Wt + (size_t)(col0 + r) * K + kh + c);
            *(uint4*)(&sW[r * KP + c]) = u;
        }
        __syncthreads();
#pragma unroll
        for (int kk = 0; kk < 128; kk += 32) {
            short8 af[2], bfr[NF];
#pragma unroll
            for (int mi = 0; mi < 2; mi++)
                af[mi] = *(const short8*)(&sA[(wr + mi * 16 + lr) * KP + kk + kg]);
#pragma unroll
            for (int ni = 0; ni < NF; ni++)
                bfr[ni] = *(const short8*)(&sW[(wc + ni * 16 + lr) * KP + kk + kg]);
#pragma unroll
            for (int mi = 0; mi < 2; mi++)
#pragma unroll
                for (int ni = 0; ni < NF; ni++)
                    acc[mi][ni] = __builtin_amdgcn_mfma_f32_16x16x32_bf16(af[mi], bfr[ni], acc[mi][ni], 0, 0, 0);
        }
        __syncthreads();
    }

    float* fs = (float*)smem;
    if (STATS) {
        if (tid < 2 * CTILE) fs[tid] = 0.f;
        __syncthreads();
    }

    float stat_s[NF], stat_q[NF];
#pragma unroll
    for (int ni = 0; ni < NF; ni++) { stat_s[ni] = 0.f; stat_q[ni] = 0.f; }

#pragma unroll
    for (int mi = 0; mi < 2; mi++) {
#pragma unroll
        for (int ni = 0; ni < NF; ni++) {
            int r = wr + mi * 16 + (lane >> 4) * 4;
            int cloc = wc + ni * 16 + (lane & 15);
            int cgl = col0 + cloc;
            float bv = bias ? bias[cgl] : 0.f;
#pragma unroll
            for (int j = 0; j < 4; j++) {
                int gr = row0 + r + j;
                if (gr < nrows) {
                    float val = acc[mi][ni][j] + bv;
                    if (rowscale) val *= rowscale[gr];
                    if (STATS) { stat_s[ni] += val; stat_q[ni] += val * val; }
                    if (HEAD) {
                        fs[(r + j) * 65 + cloc] = val;
                    } else if (OBF16) {
                        ((unsigned short*)Cv)[(size_t)gr * Dout + cgl] = f2bf(val);
                    } else {
                        ((float*)Cv)[(size_t)gr * Dout + cgl] = val;
                    }
                } else if (HEAD) {
                    fs[(r + j) * 65 + cloc] = 0.f;
                }
            }
        }
    }

    if (STATS) {
#pragma unroll
        for (int ni = 0; ni < NF; ni++) {
            int cloc = wc + ni * 16 + (lane & 15);
            atomicAdd(&fs[cloc], stat_s[ni]);
            atomicAdd(&fs[CTILE + cloc], stat_q[ni]);
        }
        __syncthreads();
        if (tid < CTILE) {
            atomicAdd(&gsum[col0 + tid], fs[tid]);
            atomicAdd(&gsq[col0 + tid], fs[CTILE + tid]);
        }
    }

    if (HEAD) {
        __syncthreads();
        for (int rr = 0; rr < 16; rr++) {
            int row = w * 16 + rr;
            int gr = row0 + row;
            if (gr >= nrows) break;
            float v = fs[row * 65 + lane];
            float m = v;
            for (int o = 32; o; o >>= 1) m = fmaxf(m, __shfl_xor(m, o));
            float e = __expf(v - m);
            float s = e;
            for (int o = 32; o; o >>= 1) s += __shfl_xor(s, o);
            ((float*)Cv)[(size_t)gr * 64 + lane] = v - m - __logf(s);
        }
    }
}

#define ACC8(u) { a0 += bflo(u.x); a1 += bfhi(u.x); a2 += bflo(u.y); a3 += bfhi(u.y); \
                  a4 += bflo(u.z); a5 += bfhi(u.z); a6 += bflo(u.w); a7 += bfhi(u.w); }

// ---------------- GCN aggregation over premultiplied p = dinv.*h, fused BN stats ----------------
__global__ __launch_bounds__(256) void k_gcn_agg(const unsigned short* __restrict__ p,
        const int* __restrict__ roff, const int* __restrict__ srcs,
        const float* __restrict__ dinv, const float* __restrict__ b,
        unsigned short* __restrict__ out,
        float* __restrict__ gsum, float* __restrict__ gsq, int N) {
    int nw = (gridDim.x * 256) >> 6;
    int wid = (blockIdx.x * 256 + threadIdx.x) >> 6;
    int lane = threadIdx.x & 63;
    int q = lane >> 4, l16 = lane & 15;
    int c = l16 * 8;
    float4 bl = *(const float4*)(b + c);
    float4 bh = *(const float4*)(b + c + 4);
    float bb[8] = {bl.x, bl.y, bl.z, bl.w, bh.x, bh.y, bh.z, bh.w};
    float ls[8] = {0,0,0,0,0,0,0,0};
    float lq[8] = {0,0,0,0,0,0,0,0};
    for (int d = wid; d < N; d += nw) {
        float a0=0.f,a1=0.f,a2=0.f,a3=0.f,a4=0.f,a5=0.f,a6=0.f,a7=0.f;
        int e0 = roff[d], e1 = roff[d + 1];
        for (int e = e0 + q; e < e1; e += 4) {
            int s = srcs[e];
            uint4 u = ((const uint4*)(p + (size_t)s * 128))[l16];
            ACC8(u);
        }
        if (q == 0) {
            uint4 u = ((const uint4*)(p + (size_t)d * 128))[l16];
            ACC8(u);
        }
        a0 += __shfl_xor(a0,16); a0 += __shfl_xor(a0,32);
        a1 += __shfl_xor(a1,16); a1 += __shfl_xor(a1,32);
        a2 += __shfl_xor(a2,16); a2 += __shfl_xor(a2,32);
        a3 += __shfl_xor(a3,16); a3 += __shfl_xor(a3,32);
        a4 += __shfl_xor(a4,16); a4 += __shfl_xor(a4,32);
        a5 += __shfl_xor(a5,16); a5 += __shfl_xor(a5,32);
        a6 += __shfl_xor(a6,16); a6 += __shfl_xor(a6,32);
        a7 += __shfl_xor(a7,16); a7 += __shfl_xor(a7,32);
        if (q == 0) {
            float dv = dinv[d];
            float r0 = dv*a0 + bb[0], r1 = dv*a1 + bb[1];
            float r2 = dv*a2 + bb[2], r3 = dv*a3 + bb[3];
            float r4 = dv*a4 + bb[4], r5 = dv*a5 + bb[5];
            float r6 = dv*a6 + bb[6], r7 = dv*a7 + bb[7];
            ls[0]+=r0; lq[0]+=r0*r0; ls[1]+=r1; lq[1]+=r1*r1;
            ls[2]+=r2; lq[2]+=r2*r2; ls[3]+=r3; lq[3]+=r3*r3;
            ls[4]+=r4; lq[4]+=r4*r4; ls[5]+=r5; lq[5]+=r5*r5;
            ls[6]+=r6; lq[6]+=r6*r6; ls[7]+=r7; lq[7]+=r7*r7;
            uint4 o;
            o.x = packbf(r0, r1); o.y = packbf(r2, r3);
            o.z = packbf(r4, r5); o.w = packbf(r6, r7);
            ((uint4*)(out + (size_t)d * 128))[l16] = o;
        }
    }
    __shared__ float sred[4][128];
    __shared__ float qred[4][128];
    int wv = threadIdx.x >> 6;
    if (q == 0) {
#pragma unroll
        for (int k = 0; k < 8; k++) { sred[wv][c + k] = ls[k]; qred[wv][c + k] = lq[k]; }
    }
    __syncthreads();
    int t = threadIdx.x;
    if (t < 128) {
        float s = sred[0][t] + sred[1][t] + sred[2][t] + sred[3][t];
        float qq = qred[0][t] + qred[1][t] + qred[2][t] + qred[3][t];
        atomicAdd(&gsum[t], s);
        atomicAdd(&gsq[t], qq);
    }
}

// ---------------- GEN precompute: per node row [w(128 bf16) | wm(128 bf16)], BN inlined ----------------
__global__ __launch_bounds__(256) void k_genpre(const unsigned short* __restrict__ t4,
        const float* __restrict__ bnsum, const float* __restrict__ bnsq,
        const float* __restrict__ bng, const float* __restrict__ bnbeta, float invN,
        unsigned short* __restrict__ wt, int N) {
    __shared__ float ssc[128], ssh[128];
    int tid = threadIdx.x;
    if (tid < 128) {
        float mu = bnsum[tid] * invN;
        float var = bnsq[tid] * invN - mu * mu;
        float s = bng[tid] * rsqrtf(var + BN_EPS);
        ssc[tid] = s; ssh[tid] = bnbeta[tid] - mu * s;
    }
    __syncthreads();
    int i = blockIdx.x * 256 + tid;
    int node = i >> 4, l16 = i & 15;
    if (node >= N) return;
    int c = l16 * 8;
    uint4 u = ((const uint4*)(t4 + (size_t)node * 128))[l16];
    float v[8] = {bflo(u.x), bfhi(u.x), bflo(u.y), bfhi(u.y),
                  bflo(u.z), bfhi(u.z), bflo(u.w), bfhi(u.w)};
    float w[8], wm[8];
#pragma unroll
    for (int k = 0; k < 8; k++) {
        float m = fmaxf(v[k] * ssc[c + k] + ssh[c + k], 0.f) + GEN_EPS;
        m = fminf(m, 80.f);
        w[k] = __expf(m);
        wm[k] = w[k] * m;
    }
    uint4* row = (uint4*)(wt + (size_t)node * 256);
    uint4 ow, om;
    ow.x = packbf(w[0], w[1]); ow.y = packbf(w[2], w[3]);
    ow.z = packbf(w[4], w[5]); ow.w = packbf(w[6], w[7]);
    om.x = packbf(wm[0], wm[1]); om.y = packbf(wm[2], wm[3]);
    om.z = packbf(wm[4], wm[5]); om.w = packbf(wm[6], wm[7]);
    row[l16] = ow;
    row[16 + l16] = om;
}

// ---------------- GEN softmax aggregation: gather w / wm rows, sum, divide; BN inlined ----------------
__global__ __launch_bounds__(256) void k_gen_agg(const unsigned short* __restrict__ t4,
        const unsigned short* __restrict__ wt,
        const int* __restrict__ roff, const int* __restrict__ srcs,
        const float* __restrict__ bnsum, const float* __restrict__ bnsq,
        const float* __restrict__ bng, const float* __restrict__ bnbeta, float invN,
        unsigned short* __restrict__ out, int N) {
    __shared__ float ssc[128], ssh[128];
    int tid = threadIdx.x;
    if (tid < 128) {
        float mu = bnsum[tid] * invN;
        float var = bnsq[tid] * invN - mu * mu;
        float s = bng[tid] * rsqrtf(var + BN_EPS);
        ssc[tid] = s; ssh[tid] = bnbeta[tid] - mu * s;
    }
    __syncthreads();
    int nw = (gridDim.x * 256) >> 6;
    int wid = (blockIdx.x * 256 + tid) >> 6;
    int lane = tid & 63;
    int q = lane >> 4, l16 = lane & 15;
    int c = l16 * 8;
    for (int d = wid; d < N; d += nw) {
        float de[8] = {0,0,0,0,0,0,0,0};
        float nu[8] = {0,0,0,0,0,0,0,0};
        int e0 = roff[d], e1 = roff[d + 1];
        for (int e = e0 + q; e < e1; e += 4) {
            int s = srcs[e];
            const uint4* row = (const uint4*)(wt + (size_t)s * 256);
            uint4 uw = row[l16];
            uint4 um = row[16 + l16];
            de[0] += bflo(uw.x); de[1] += bfhi(uw.x);
            de[2] += bflo(uw.y); de[3] += bfhi(uw.y);
            de[4] += bflo(uw.z); de[5] += bfhi(uw.z);
            de[6] += bflo(uw.w); de[7] += bfhi(uw.w);
            nu[0] += bflo(um.x); nu[1] += bfhi(um.x);
            nu[2] += bflo(um.y); nu[3] += bfhi(um.y);
            nu[4] += bflo(um.z); nu[5] += bfhi(um.z);
            nu[6] += bflo(um.w); nu[7] += bfhi(um.w);
        }
#pragma unroll
        for (int k = 0; k < 8; k++) {
            de[k] += __shfl_xor(de[k],16); de[k] += __shfl_xor(de[k],32);
            nu[k] += __shfl_xor(nu[k],16); nu[k] += __shfl_xor(nu[k],32);
        }
        if (q == 0) {
            uint4 u = ((const uint4*)(t4 + (size_t)d * 128))[l16];
            float v[8] = {bflo(u.x), bfhi(u.x), bflo(u.y), bfhi(u.y),
                          bflo(u.z), bfhi(u.z), bflo(u.w), bfhi(u.w)};
            float r[8];
            bool has = (e1 > e0);
#pragma unroll
            for (int k = 0; k < 8; k++) {
                float h2 = fmaxf(v[k] * ssc[c + k] + ssh[c + k], 0.f);
                float a = has ? nu[k] / de[k] : 0.f;
                r[k] = a + h2;
            }
            uint4 o;
            o.x = packbf(r[0], r[1]); o.y = packbf(r[2], r[3]);
            o.z = packbf(r[4], r[5]); o.w = packbf(r[6], r[7]);
            ((uint4*)(out + (size_t)d * 128))[l16] = o;
        }
    }
}

extern "C" void kernel_launch(void* const* d_in, const int* in_sizes, int n_in,
                              void* d_out, int out_size, void* d_ws, size_t ws_size,
                              hipStream_t stream) {
    const float* x   = (const float*)d_in[0];
    const float* W0  = (const float*)d_in[1];
    const float* b0  = (const float*)d_in[2];
    const float* g0  = (const float*)d_in[3];
    const float* be0 = (const float*)d_in[4];
    const float* W1  = (const float*)d_in[5];
    const float* b1  = (const float*)d_in[6];
    const float* g1  = (const float*)d_in[7];
    const float* be1 = (const float*)d_in[8];
    const float* Wg1 = (const float*)d_in[9];
    const float* bg1 = (const float*)d_in[10];
    const float* gg  = (const float*)d_in[11];
    const float* beg = (const float*)d_in[12];
    const float* Wg2 = (const float*)d_in[13];
    const float* bg2 = (const float*)d_in[14];
    const int*   ei  = (const int*)d_in[15];

    const int N = in_sizes[0] / DIN;
    const int E = in_sizes[15] / 2;
    const int* srce = ei;
    const int* dste = ei + E;

    char* ws = (char*)d_ws;
    size_t off = 0;
    auto alloc = [&](size_t b) { size_t o = off; off = (off + b + 255) & ~(size_t)255; return o; };
    size_t o_counts = alloc((size_t)N * 4);
    size_t o_stats  = alloc(1024 * 4);
    size_t o_cursor = alloc((size_t)N * 4);
    size_t o_roff   = alloc(((size_t)N + 1) * 4);
    size_t o_srcs   = alloc((size_t)E * 4);
    size_t o_dinv   = alloc((size_t)N * 4);
    size_t o_bsum   = alloc(1024 * 4);
    size_t o_w0t    = alloc(128 * 128 * 2);
    size_t o_w1t    = alloc(128 * 128 * 2);
    size_t o_wg1t   = alloc(256 * 128 * 2);
    size_t o_wg2t   = alloc(64 * 256 * 2);
    size_t o_xa     = alloc((size_t)N * 128 * 2);
    size_t o_xb     = alloc((size_t)N * 128 * 2);
    size_t o_c      = alloc((size_t)N * 256 * 2);   // MLP hidden; aliased as GEN exp table
    (void)ws_size; (void)n_in; (void)out_size;

    int* counts = (int*)(ws + o_counts);
    float* stats = (float*)(ws + o_stats);
    int* cursor = (int*)(ws + o_cursor);
    int* roff = (int*)(ws + o_roff);
    int* srcs = (int*)(ws + o_srcs);
    float* dinv = (float*)(ws + o_dinv);
    int* bsum = (int*)(ws + o_bsum);
    unsigned short* w0t  = (unsigned short*)(ws + o_w0t);
    unsigned short* w1t  = (unsigned short*)(ws + o_w1t);
    unsigned short* wg1t = (unsigned short*)(ws + o_wg1t);
    unsigned short* wg2t = (unsigned short*)(ws + o_wg2t);
    unsigned short* xa = (unsigned short*)(ws + o_xa);
    unsigned short* xb = (unsigned short*)(ws + o_xb);
    unsigned short* cb = (unsigned short*)(ws + o_c);
    unsigned short* wtab = cb;  // alias: w/wm table lives in cb until MLP GEMM overwrites it

    float* sum0 = stats;       float* sq0 = stats + 128;
    float* sum1 = stats + 256; float* sq1 = stats + 384;
    float* sumg = stats + 512; float* sqg = stats + 768;

    // CSR build + zeroing: single cooperative kernel (6 grid-synced phases)
    {
        int NPeople = N, EE = E;
        void* args[] = { (void*)&srce, (void*)&dste, (void*)&counts, (void*)&cursor,
                         (void*)&roff, (void*)&bsum, (void*)&srcs, (void*)&dinv,
                         (void*)&stats, (void*)&NPeople, (void*)&EE };
        hipLaunchCooperativeKernel((void*)k_csr, dim3(1024), dim3(256), args, 0, stream);
    }

    // all weight transposes (bf16), one launch
    k_wt_all<<<320, 256, 0, stream>>>(W0, W1, Wg1, Wg2, w0t, w1t, wg1t, wg2t);

    int rb = (N + 63) / 64;
    const float invN = 1.f / (float)N;

    // layer 0: p0 = dinv.*(x@W0) -> xa ; agg (+fused stats) -> xb
    k_gemm<128, 128, false, true, false, false, false><<<dim3(rb, 1), 256, 0, stream>>>(
        x, w0t, nullptr, nullptr, nullptr, nullptr, nullptr, 0.f, dinv, xa, nullptr, nullptr, N, 128);
    k_gcn_agg<<<2048, 256, 0, stream>>>(xa, roff, srcs, dinv, b0, xb, sum0, sq0, N);

    // layer 1: BN0 finalize inlined in GEMM
    k_gemm<128, 128, true, true, false, false, true><<<dim3(rb, 1), 256, 0, stream>>>(
        xb, w1t, nullptr, sum0, sq0, g0, be0, invN, dinv, xa, nullptr, nullptr, N, 128);
    k_gcn_agg<<<2048, 256, 0, stream>>>(xa, roff, srcs, dinv, b1, xb, sum1, sq1, N);

    // GEN conv: w/wm table (BN1 inlined), then gather-sum
    k_genpre<<<(N * 16 + 255) / 256, 256, 0, stream>>>(xb, sum1, sq1, g1, be1, invN, wtab, N);
    k_gen_agg<<<2048, 256, 0, stream>>>(xb, wtab, roff, srcs, sum1, sq1, g1, be1, invN, xa, N);

    // MLP: t7 = t6@Wg1+bg1 -> cb (overwrites w-table), stats fused
    k_gemm<128, 128, true, true, true, false, false><<<dim3(rb, 2), 256, 0, stream>>>(
        xa, wg1t, bg1, nullptr, nullptr, nullptr, nullptr, 0.f, nullptr, cb, sumg, sqg, N, 256);

    // final GEMM: BNg finalize inlined + fused log_softmax -> d_out
    k_gemm<256, 64, true, false, false, true, true><<<dim3(rb, 1), 256, 0, stream>>>(
        cb, wg2t, bg2, sumg, sqg, gg, beg, invN, nullptr, d_out, nullptr, nullptr, N, 64);
}

// Round 11
// 468.510 us; speedup vs baseline: 1.9954x; 1.9954x over previous
//
#include <hip/hip_runtime.h>
#include <hip/hip_bf16.h>

#define DIN 128
#define DHID 128
#define DCLS 64
#define BN_EPS 1e-5f
#define GEN_EPS 1e-7f

typedef __attribute__((ext_vector_type(8))) short short8;
typedef __attribute__((ext_vector_type(4))) float f32x4;

static __device__ __forceinline__ float bf2f(unsigned short u) {
    union { float f; unsigned int i; } x; x.i = ((unsigned int)u) << 16; return x.f;
}
static __device__ __forceinline__ unsigned short f2bf(float f) {
    union { float f; unsigned int i; } x; x.f = f;
    unsigned int r = x.i + 0x7fffu + ((x.i >> 16) & 1u);
    return (unsigned short)(r >> 16);
}
static __device__ __forceinline__ float bflo(unsigned int u) {
    union { float f; unsigned int i; } x; x.i = u << 16; return x.f;
}
static __device__ __forceinline__ float bfhi(unsigned int u) {
    union { float f; unsigned int i; } x; x.i = u & 0xffff0000u; return x.f;
}
static __device__ __forceinline__ unsigned int packbf(float lo, float hi) {
    return ((unsigned int)f2bf(hi) << 16) | f2bf(lo);
}

// ---------------- CSR build (separate launches — r10 coop-kernel was 7x slower) ----------------
__global__ void k_hist(const int* __restrict__ dst, int* __restrict__ counts, int E) {
    int e = blockIdx.x * 256 + threadIdx.x;
    if (e < E) atomicAdd(&counts[dst[e]], 1);
}

__global__ __launch_bounds__(256) void k_scan1(const int* __restrict__ counts,
        int* __restrict__ roff, int* __restrict__ bsum, int N) {
    __shared__ int ls[256];
    int t = threadIdx.x;
    int base = blockIdx.x * 1024 + t * 4;
    int c0 = 0, c1 = 0, c2 = 0, c3 = 0;
    if (base + 3 < N) {
        int4 v = *(const int4*)(counts + base);
        c0 = v.x; c1 = v.y; c2 = v.z; c3 = v.w;
    } else {
        if (base + 0 < N) c0 = counts[base + 0];
        if (base + 1 < N) c1 = counts[base + 1];
        if (base + 2 < N) c2 = counts[base + 2];
        if (base + 3 < N) c3 = counts[base + 3];
    }
    ls[t] = c0 + c1 + c2 + c3;
    __syncthreads();
    for (int off = 1; off < 256; off <<= 1) {
        int v = (t >= off) ? ls[t - off] : 0;
        __syncthreads();
        ls[t] += v;
        __syncthreads();
    }
    int r = (t == 0) ? 0 : ls[t - 1];
    if (base + 0 < N) { roff[base + 0] = r; r += c0; }
    if (base + 1 < N) { roff[base + 1] = r; r += c1; }
    if (base + 2 < N) { roff[base + 2] = r; r += c2; }
    if (base + 3 < N) { roff[base + 3] = r; }
    if (t == 255) bsum[blockIdx.x] = ls[255];
}

// scan3 with inlined block-sum prefix (nblk ~49, serial per block is cheap)
__global__ void k_scan3(const int* __restrict__ counts, const int* __restrict__ bsum,
        int* __restrict__ roff, int* __restrict__ cursor, float* __restrict__ dinv,
        int N, int E) {
    __shared__ int sbase;
    if (threadIdx.x == 0) {
        int blk = (blockIdx.x * 256) >> 10;
        int s = 0;
        for (int j = 0; j < blk; j++) s += bsum[j];
        sbase = s;
    }
    __syncthreads();
    int i = blockIdx.x * 256 + threadIdx.x;
    if (i < N) {
        int r = roff[i] + sbase;
        roff[i] = r; cursor[i] = r;
        dinv[i] = rsqrtf((float)(counts[i] + 1));
    }
    if (i == 0) roff[N] = E;
}

__global__ void k_fill(const int* __restrict__ src, const int* __restrict__ dst,
        int* __restrict__ cursor, int* __restrict__ srcs, int E) {
    int e = blockIdx.x * 256 + threadIdx.x;
    if (e < E) {
        int d = dst[e];
        int p = atomicAdd(&cursor[d], 1);
        srcs[p] = src[e];
    }
}

// ---------------- all four weight transposes in one launch ----------------
__global__ void k_wt_all(const float* __restrict__ W0, const float* __restrict__ W1,
        const float* __restrict__ Wg1, const float* __restrict__ Wg2,
        unsigned short* __restrict__ w0t, unsigned short* __restrict__ w1t,
        unsigned short* __restrict__ wg1t, unsigned short* __restrict__ wg2t) {
    int i = blockIdx.x * 256 + threadIdx.x;
    const float* W; unsigned short* Wt; int Kk, Dd, j;
    if (i < 16384)      { W = W0;  Wt = w0t;  Kk = 128; Dd = 128; j = i; }
    else if (i < 32768) { W = W1;  Wt = w1t;  Kk = 128; Dd = 128; j = i - 16384; }
    else if (i < 65536) { W = Wg1; Wt = wg1t; Kk = 128; Dd = 256; j = i - 32768; }
    else if (i < 81920) { W = Wg2; Wt = wg2t; Kk = 256; Dd = 64;  j = i - 65536; }
    else return;
    int n = j / Kk, k = j - n * Kk;
    Wt[j] = f2bf(W[(size_t)k * Dd + n]);
}

// ---------------- GEMM: C[nrows,Dout] = op(A)[nrows,K] @ W[K,Dout] (+bias, *rowscale) ----------------
// SFIN: BN finalize inlined (scale/shift from raw sums in LDS preamble, relu fused on A).
// STATS: fuse per-column sum/sumsq of outputs via LDS + global atomics.
// HEAD: fuse row log_softmax (requires CTILE == Dout == 64, f32 out).
template<int K, int CTILE, bool ABF16, bool OBF16, bool STATS, bool HEAD, bool SFIN>
__global__ __launch_bounds__(256) void k_gemm(const void* __restrict__ Av,
        const unsigned short* __restrict__ Wt, const float* __restrict__ bias,
        const float* __restrict__ bnsum, const float* __restrict__ bnsq,
        const float* __restrict__ bng, const float* __restrict__ bnbeta, float invN,
        const float* __restrict__ rowscale,
        void* __restrict__ Cv, float* __restrict__ gsum, float* __restrict__ gsq,
        int nrows, int Dout) {
    constexpr int KP = 136;
    constexpr int NF = CTILE / 32;
    constexpr int BNSZ = SFIN ? 2 * K : 2;
    __shared__ unsigned short smem[(64 + CTILE) * KP];
    __shared__ float sBN[BNSZ];
    unsigned short* sA = smem;
    unsigned short* sW = smem + 64 * KP;
    const int tid = threadIdx.x;
    const int row0 = blockIdx.x * 64, col0 = blockIdx.y * CTILE;

    if (SFIN) {
        for (int c = tid; c < K; c += 256) {
            float mu = bnsum[c] * invN;
            float var = bnsq[c] * invN - mu * mu;
            float s = bng[c] * rsqrtf(var + BN_EPS);
            sBN[c] = s; sBN[K + c] = bnbeta[c] - mu * s;
        }
        __syncthreads();
    }

    const int w = tid >> 6, lane = tid & 63;
    const int wr = (w >> 1) * 32, wc = (w & 1) * (CTILE / 2);
    const int lr = lane & 15, kg = (lane >> 4) * 8;
    f32x4 acc[2][NF] = {};

    for (int kh = 0; kh < K; kh += 128) {
#pragma unroll
        for (int it = 0; it < 8; ++it) {
            int idx = (it * 256 + tid) * 4;
            int r = idx >> 7, c = idx & 127;
            int gr = row0 + r;
            float v0 = 0.f, v1 = 0.f, v2 = 0.f, v3 = 0.f;
            if (gr < nrows) {
                if (ABF16) {
                    ushort4 u = *(const ushort4*)((const unsigned short*)Av + (size_t)gr * K + kh + c);
                    v0 = bf2f(u.x); v1 = bf2f(u.y); v2 = bf2f(u.z); v3 = bf2f(u.w);
                } else {
                    float4 f = *(const float4*)((const float*)Av + (size_t)gr * K + kh + c);
                    v0 = f.x; v1 = f.y; v2 = f.z; v3 = f.w;
                }
                if (SFIN) {
                    int cc = kh + c;
                    v0 = fmaxf(v0 * sBN[cc + 0] + sBN[K + cc + 0], 0.f);
                    v1 = fmaxf(v1 * sBN[cc + 1] + sBN[K + cc + 1], 0.f);
                    v2 = fmaxf(v2 * sBN[cc + 2] + sBN[K + cc + 2], 0.f);
                    v3 = fmaxf(v3 * sBN[cc + 3] + sBN[K + cc + 3], 0.f);
                }
            }
            ushort4 o; o.x = f2bf(v0); o.y = f2bf(v1); o.z = f2bf(v2); o.w = f2bf(v3);
            *(ushort4*)(&sA[r * KP + c]) = o;
        }
#pragma unroll
        for (int it = 0; it < (CTILE * 128) / (256 * 8); ++it) {
            int idx = (it * 256 + tid) * 8;
            int r = idx >> 7, c = idx & 127;
            uint4 u = *(const uint4*)(Wt + (size_t)(col0 + r) * K + kh + c);
            *(uint4*)(&sW[r * KP + c]) = u;
        }
        __syncthreads();
#pragma unroll
        for (int kk = 0; kk < 128; kk += 32) {
            short8 af[2], bfr[NF];
#pragma unroll
            for (int mi = 0; mi < 2; mi++)
                af[mi] = *(const short8*)(&sA[(wr + mi * 16 + lr) * KP + kk + kg]);
#pragma unroll
            for (int ni = 0; ni < NF; ni++)
                bfr[ni] = *(const short8*)(&sW[(wc + ni * 16 + lr) * KP + kk + kg]);
#pragma unroll
            for (int mi = 0; mi < 2; mi++)
#pragma unroll
                for (int ni = 0; ni < NF; ni++)
                    acc[mi][ni] = __builtin_amdgcn_mfma_f32_16x16x32_bf16(af[mi], bfr[ni], acc[mi][ni], 0, 0, 0);
        }
        __syncthreads();
    }

    float* fs = (float*)smem;
    if (STATS) {
        if (tid < 2 * CTILE) fs[tid] = 0.f;
        __syncthreads();
    }

    float stat_s[NF], stat_q[NF];
#pragma unroll
    for (int ni = 0; ni < NF; ni++) { stat_s[ni] = 0.f; stat_q[ni] = 0.f; }

#pragma unroll
    for (int mi = 0; mi < 2; mi++) {
#pragma unroll
        for (int ni = 0; ni < NF; ni++) {
            int r = wr + mi * 16 + (lane >> 4) * 4;
            int cloc = wc + ni * 16 + (lane & 15);
            int cgl = col0 + cloc;
            float bv = bias ? bias[cgl] : 0.f;
#pragma unroll
            for (int j = 0; j < 4; j++) {
                int gr = row0 + r + j;
                if (gr < nrows) {
                    float val = acc[mi][ni][j] + bv;
                    if (rowscale) val *= rowscale[gr];
                    if (STATS) { stat_s[ni] += val; stat_q[ni] += val * val; }
                    if (HEAD) {
                        fs[(r + j) * 65 + cloc] = val;
                    } else if (OBF16) {
                        ((unsigned short*)Cv)[(size_t)gr * Dout + cgl] = f2bf(val);
                    } else {
                        ((float*)Cv)[(size_t)gr * Dout + cgl] = val;
                    }
                } else if (HEAD) {
                    fs[(r + j) * 65 + cloc] = 0.f;
                }
            }
        }
    }

    if (STATS) {
#pragma unroll
        for (int ni = 0; ni < NF; ni++) {
            int cloc = wc + ni * 16 + (lane & 15);
            atomicAdd(&fs[cloc], stat_s[ni]);
            atomicAdd(&fs[CTILE + cloc], stat_q[ni]);
        }
        __syncthreads();
        if (tid < CTILE) {
            atomicAdd(&gsum[col0 + tid], fs[tid]);
            atomicAdd(&gsq[col0 + tid], fs[CTILE + tid]);
        }
    }

    if (HEAD) {
        __syncthreads();
        for (int rr = 0; rr < 16; rr++) {
            int row = w * 16 + rr;
            int gr = row0 + row;
            if (gr >= nrows) break;
            float v = fs[row * 65 + lane];
            float m = v;
            for (int o = 32; o; o >>= 1) m = fmaxf(m, __shfl_xor(m, o));
            float e = __expf(v - m);
            float s = e;
            for (int o = 32; o; o >>= 1) s += __shfl_xor(s, o);
            ((float*)Cv)[(size_t)gr * 64 + lane] = v - m - __logf(s);
        }
    }
}

#define ACC8(u) { a0 += bflo(u.x); a1 += bfhi(u.x); a2 += bflo(u.y); a3 += bfhi(u.y); \
                  a4 += bflo(u.z); a5 += bfhi(u.z); a6 += bflo(u.w); a7 += bfhi(u.w); }

// ---------------- GCN aggregation over premultiplied p = dinv.*h, fused BN stats ----------------
__global__ __launch_bounds__(256) void k_gcn_agg(const unsigned short* __restrict__ p,
        const int* __restrict__ roff, const int* __restrict__ srcs,
        const float* __restrict__ dinv, const float* __restrict__ b,
        unsigned short* __restrict__ out,
        float* __restrict__ gsum, float* __restrict__ gsq, int N) {
    int nw = (gridDim.x * 256) >> 6;
    int wid = (blockIdx.x * 256 + threadIdx.x) >> 6;
    int lane = threadIdx.x & 63;
    int q = lane >> 4, l16 = lane & 15;
    int c = l16 * 8;
    float4 bl = *(const float4*)(b + c);
    float4 bh = *(const float4*)(b + c + 4);
    float bb[8] = {bl.x, bl.y, bl.z, bl.w, bh.x, bh.y, bh.z, bh.w};
    float ls[8] = {0,0,0,0,0,0,0,0};
    float lq[8] = {0,0,0,0,0,0,0,0};
    for (int d = wid; d < N; d += nw) {
        float a0=0.f,a1=0.f,a2=0.f,a3=0.f,a4=0.f,a5=0.f,a6=0.f,a7=0.f;
        int e0 = roff[d], e1 = roff[d + 1];
        for (int e = e0 + q; e < e1; e += 4) {
            int s = srcs[e];
            uint4 u = ((const uint4*)(p + (size_t)s * 128))[l16];
            ACC8(u);
        }
        if (q == 0) {
            uint4 u = ((const uint4*)(p + (size_t)d * 128))[l16];
            ACC8(u);
        }
        a0 += __shfl_xor(a0,16); a0 += __shfl_xor(a0,32);
        a1 += __shfl_xor(a1,16); a1 += __shfl_xor(a1,32);
        a2 += __shfl_xor(a2,16); a2 += __shfl_xor(a2,32);
        a3 += __shfl_xor(a3,16); a3 += __shfl_xor(a3,32);
        a4 += __shfl_xor(a4,16); a4 += __shfl_xor(a4,32);
        a5 += __shfl_xor(a5,16); a5 += __shfl_xor(a5,32);
        a6 += __shfl_xor(a6,16); a6 += __shfl_xor(a6,32);
        a7 += __shfl_xor(a7,16); a7 += __shfl_xor(a7,32);
        if (q == 0) {
            float dv = dinv[d];
            float r0 = dv*a0 + bb[0], r1 = dv*a1 + bb[1];
            float r2 = dv*a2 + bb[2], r3 = dv*a3 + bb[3];
            float r4 = dv*a4 + bb[4], r5 = dv*a5 + bb[5];
            float r6 = dv*a6 + bb[6], r7 = dv*a7 + bb[7];
            ls[0]+=r0; lq[0]+=r0*r0; ls[1]+=r1; lq[1]+=r1*r1;
            ls[2]+=r2; lq[2]+=r2*r2; ls[3]+=r3; lq[3]+=r3*r3;
            ls[4]+=r4; lq[4]+=r4*r4; ls[5]+=r5; lq[5]+=r5*r5;
            ls[6]+=r6; lq[6]+=r6*r6; ls[7]+=r7; lq[7]+=r7*r7;
            uint4 o;
            o.x = packbf(r0, r1); o.y = packbf(r2, r3);
            o.z = packbf(r4, r5); o.w = packbf(r6, r7);
            ((uint4*)(out + (size_t)d * 128))[l16] = o;
        }
    }
    __shared__ float sred[4][128];
    __shared__ float qred[4][128];
    int wv = threadIdx.x >> 6;
    if (q == 0) {
#pragma unroll
        for (int k = 0; k < 8; k++) { sred[wv][c + k] = ls[k]; qred[wv][c + k] = lq[k]; }
    }
    __syncthreads();
    int t = threadIdx.x;
    if (t < 128) {
        float s = sred[0][t] + sred[1][t] + sred[2][t] + sred[3][t];
        float qq = qred[0][t] + qred[1][t] + qred[2][t] + qred[3][t];
        atomicAdd(&gsum[t], s);
        atomicAdd(&gsq[t], qq);
    }
}

// ---------------- GEN precompute: per node row [w(128 bf16) | wm(128 bf16)], BN inlined ----------------
__global__ __launch_bounds__(256) void k_genpre(const unsigned short* __restrict__ t4,
        const float* __restrict__ bnsum, const float* __restrict__ bnsq,
        const float* __restrict__ bng, const float* __restrict__ bnbeta, float invN,
        unsigned short* __restrict__ wt, int N) {
    __shared__ float ssc[128], ssh[128];
    int tid = threadIdx.x;
    if (tid < 128) {
        float mu = bnsum[tid] * invN;
        float var = bnsq[tid] * invN - mu * mu;
        float s = bng[tid] * rsqrtf(var + BN_EPS);
        ssc[tid] = s; ssh[tid] = bnbeta[tid] - mu * s;
    }
    __syncthreads();
    int i = blockIdx.x * 256 + tid;
    int node = i >> 4, l16 = i & 15;
    if (node >= N) return;
    int c = l16 * 8;
    uint4 u = ((const uint4*)(t4 + (size_t)node * 128))[l16];
    float v[8] = {bflo(u.x), bfhi(u.x), bflo(u.y), bfhi(u.y),
                  bflo(u.z), bfhi(u.z), bflo(u.w), bfhi(u.w)};
    float w[8], wm[8];
#pragma unroll
    for (int k = 0; k < 8; k++) {
        float m = fmaxf(v[k] * ssc[c + k] + ssh[c + k], 0.f) + GEN_EPS;
        m = fminf(m, 80.f);
        w[k] = __expf(m);
        wm[k] = w[k] * m;
    }
    uint4* row = (uint4*)(wt + (size_t)node * 256);
    uint4 ow, om;
    ow.x = packbf(w[0], w[1]); ow.y = packbf(w[2], w[3]);
    ow.z = packbf(w[4], w[5]); ow.w = packbf(w[6], w[7]);
    om.x = packbf(wm[0], wm[1]); om.y = packbf(wm[2], wm[3]);
    om.z = packbf(wm[4], wm[5]); om.w = packbf(wm[6], wm[7]);
    row[l16] = ow;
    row[16 + l16] = om;
}

// ---------------- GEN softmax aggregation: gather w / wm rows, sum, divide; BN inlined ----------------
__global__ __launch_bounds__(256) void k_gen_agg(const unsigned short* __restrict__ t4,
        const unsigned short* __restrict__ wt,
        const int* __restrict__ roff, const int* __restrict__ srcs,
        const float* __restrict__ bnsum, const float* __restrict__ bnsq,
        const float* __restrict__ bng, const float* __restrict__ bnbeta, float invN,
        unsigned short* __restrict__ out, int N) {
    __shared__ float ssc[128], ssh[128];
    int tid = threadIdx.x;
    if (tid < 128) {
        float mu = bnsum[tid] * invN;
        float var = bnsq[tid] * invN - mu * mu;
        float s = bng[tid] * rsqrtf(var + BN_EPS);
        ssc[tid] = s; ssh[tid] = bnbeta[tid] - mu * s;
    }
    __syncthreads();
    int nw = (gridDim.x * 256) >> 6;
    int wid = (blockIdx.x * 256 + tid) >> 6;
    int lane = tid & 63;
    int q = lane >> 4, l16 = lane & 15;
    int c = l16 * 8;
    for (int d = wid; d < N; d += nw) {
        float de[8] = {0,0,0,0,0,0,0,0};
        float nu[8] = {0,0,0,0,0,0,0,0};
        int e0 = roff[d], e1 = roff[d + 1];
        for (int e = e0 + q; e < e1; e += 4) {
            int s = srcs[e];
            const uint4* row = (const uint4*)(wt + (size_t)s * 256);
            uint4 uw = row[l16];
            uint4 um = row[16 + l16];
            de[0] += bflo(uw.x); de[1] += bfhi(uw.x);
            de[2] += bflo(uw.y); de[3] += bfhi(uw.y);
            de[4] += bflo(uw.z); de[5] += bfhi(uw.z);
            de[6] += bflo(uw.w); de[7] += bfhi(uw.w);
            nu[0] += bflo(um.x); nu[1] += bfhi(um.x);
            nu[2] += bflo(um.y); nu[3] += bfhi(um.y);
            nu[4] += bflo(um.z); nu[5] += bfhi(um.z);
            nu[6] += bflo(um.w); nu[7] += bfhi(um.w);
        }
#pragma unroll
        for (int k = 0; k < 8; k++) {
            de[k] += __shfl_xor(de[k],16); de[k] += __shfl_xor(de[k],32);
            nu[k] += __shfl_xor(nu[k],16); nu[k] += __shfl_xor(nu[k],32);
        }
        if (q == 0) {
            uint4 u = ((const uint4*)(t4 + (size_t)d * 128))[l16];
            float v[8] = {bflo(u.x), bfhi(u.x), bflo(u.y), bfhi(u.y),
                          bflo(u.z), bfhi(u.z), bflo(u.w), bfhi(u.w)};
            float r[8];
            bool has = (e1 > e0);
#pragma unroll
            for (int k = 0; k < 8; k++) {
                float h2 = fmaxf(v[k] * ssc[c + k] + ssh[c + k], 0.f);
                float a = has ? nu[k] / de[k] : 0.f;
                r[k] = a + h2;
            }
            uint4 o;
            o.x = packbf(r[0], r[1]); o.y = packbf(r[2], r[3]);
            o.z = packbf(r[4], r[5]); o.w = packbf(r[6], r[7]);
            ((uint4*)(out + (size_t)d * 128))[l16] = o;
        }
    }
}

extern "C" void kernel_launch(void* const* d_in, const int* in_sizes, int n_in,
                              void* d_out, int out_size, void* d_ws, size_t ws_size,
                              hipStream_t stream) {
    const float* x   = (const float*)d_in[0];
    const float* W0  = (const float*)d_in[1];
    const float* b0  = (const float*)d_in[2];
    const float* g0  = (const float*)d_in[3];
    const float* be0 = (const float*)d_in[4];
    const float* W1  = (const float*)d_in[5];
    const float* b1  = (const float*)d_in[6];
    const float* g1  = (const float*)d_in[7];
    const float* be1 = (const float*)d_in[8];
    const float* Wg1 = (const float*)d_in[9];
    const float* bg1 = (const float*)d_in[10];
    const float* gg  = (const float*)d_in[11];
    const float* beg = (const float*)d_in[12];
    const float* Wg2 = (const float*)d_in[13];
    const float* bg2 = (const float*)d_in[14];
    const int*   ei  = (const int*)d_in[15];

    const int N = in_sizes[0] / DIN;
    const int E = in_sizes[15] / 2;
    const int* srce = ei;
    const int* dste = ei + E;

    char* ws = (char*)d_ws;
    size_t off = 0;
    auto alloc = [&](size_t b) { size_t o = off; off = (off + b + 255) & ~(size_t)255; return o; };
    size_t o_counts = alloc((size_t)N * 4);
    size_t o_stats  = alloc(1024 * 4);
    size_t o_cursor = alloc((size_t)N * 4);
    size_t o_roff   = alloc(((size_t)N + 1) * 4);
    size_t o_srcs   = alloc((size_t)E * 4);
    size_t o_dinv   = alloc((size_t)N * 4);
    size_t o_bsum   = alloc(1024 * 4);
    size_t o_w0t    = alloc(128 * 128 * 2);
    size_t o_w1t    = alloc(128 * 128 * 2);
    size_t o_wg1t   = alloc(256 * 128 * 2);
    size_t o_wg2t   = alloc(64 * 256 * 2);
    size_t o_xa     = alloc((size_t)N * 128 * 2);
    size_t o_xb     = alloc((size_t)N * 128 * 2);
    size_t o_c      = alloc((size_t)N * 256 * 2);   // MLP hidden; aliased as GEN exp table
    (void)ws_size; (void)n_in; (void)out_size;

    int* counts = (int*)(ws + o_counts);
    float* stats = (float*)(ws + o_stats);
    int* cursor = (int*)(ws + o_cursor);
    int* roff = (int*)(ws + o_roff);
    int* srcs = (int*)(ws + o_srcs);
    float* dinv = (float*)(ws + o_dinv);
    int* bsum = (int*)(ws + o_bsum);
    unsigned short* w0t  = (unsigned short*)(ws + o_w0t);
    unsigned short* w1t  = (unsigned short*)(ws + o_w1t);
    unsigned short* wg1t = (unsigned short*)(ws + o_wg1t);
    unsigned short* wg2t = (unsigned short*)(ws + o_wg2t);
    unsigned short* xa = (unsigned short*)(ws + o_xa);
    unsigned short* xb = (unsigned short*)(ws + o_xb);
    unsigned short* cb = (unsigned short*)(ws + o_c);
    unsigned short* wtab = cb;  // alias: w/wm table lives in cb until MLP GEMM overwrites it

    float* sum0 = stats;       float* sq0 = stats + 128;
    float* sum1 = stats + 256; float* sq1 = stats + 384;
    float* sumg = stats + 512; float* sqg = stats + 768;

    // zero counts + stats (contiguous region)
    hipMemsetAsync(ws + o_counts, 0, o_cursor - o_counts, stream);

    // CSR build (separate launches)
    int egrid = (E + 255) / 256;
    int nblk = (N + 1023) / 1024;
    k_hist<<<egrid, 256, 0, stream>>>(dste, counts, E);
    k_scan1<<<nblk, 256, 0, stream>>>(counts, roff, bsum, N);
    k_scan3<<<(N + 255) / 256, 256, 0, stream>>>(counts, bsum, roff, cursor, dinv, N, E);
    k_fill<<<egrid, 256, 0, stream>>>(srce, dste, cursor, srcs, E);

    // all weight transposes (bf16), one launch
    k_wt_all<<<320, 256, 0, stream>>>(W0, W1, Wg1, Wg2, w0t, w1t, wg1t, wg2t);

    int rb = (N + 63) / 64;
    const float invN = 1.f / (float)N;

    // layer 0: p0 = dinv.*(x@W0) -> xa ; agg (+fused stats) -> xb
    k_gemm<128, 128, false, true, false, false, false><<<dim3(rb, 1), 256, 0, stream>>>(
        x, w0t, nullptr, nullptr, nullptr, nullptr, nullptr, 0.f, dinv, xa, nullptr, nullptr, N, 128);
    k_gcn_agg<<<2048, 256, 0, stream>>>(xa, roff, srcs, dinv, b0, xb, sum0, sq0, N);

    // layer 1: BN0 finalize inlined in GEMM
    k_gemm<128, 128, true, true, false, false, true><<<dim3(rb, 1), 256, 0, stream>>>(
        xb, w1t, nullptr, sum0, sq0, g0, be0, invN, dinv, xa, nullptr, nullptr, N, 128);
    k_gcn_agg<<<2048, 256, 0, stream>>>(xa, roff, srcs, dinv, b1, xb, sum1, sq1, N);

    // GEN conv: w/wm table (BN1 inlined), then gather-sum
    k_genpre<<<(N * 16 + 255) / 256, 256, 0, stream>>>(xb, sum1, sq1, g1, be1, invN, wtab, N);
    k_gen_agg<<<2048, 256, 0, stream>>>(xb, wtab, roff, srcs, sum1, sq1, g1, be1, invN, xa, N);

    // MLP: t7 = t6@Wg1+bg1 -> cb (overwrites w-table), stats fused
    k_gemm<128, 128, true, true, true, false, false><<<dim3(rb, 2), 256, 0, stream>>>(
        xa, wg1t, bg1, nullptr, nullptr, nullptr, nullptr, 0.f, nullptr, cb, sumg, sqg, N, 256);

    // final GEMM: BNg finalize inlined + fused log_softmax -> d_out
    k_gemm<256, 64, true, false, false, true, true><<<dim3(rb, 1), 256, 0, stream>>>(
        cb, wg2t, bg2, sumg, sqg, gg, beg, invN, nullptr, d_out, nullptr, nullptr, N, 64);
}